// Round 4
// baseline (247.421 us; speedup 1.0000x reference)
//
#include <hip/hip_runtime.h>

// Problem constants
#define NB 128
#define NL 1024
#define NE 512
#define NA 512
#define ND 512

typedef __attribute__((ext_vector_type(8))) short short8;
typedef __attribute__((ext_vector_type(4))) float f32x4;

static __device__ __forceinline__ unsigned short f2bf(float f) {
  unsigned int u = __float_as_uint(f);
  u += 0x7FFF + ((u >> 16) & 1);   // round-to-nearest-even
  return (unsigned short)(u >> 16);
}

// async global->LDS, 16B per lane (wave-uniform LDS base + lane*16)
static __device__ __forceinline__ void async_cp16(const void* g, void* l) {
  __builtin_amdgcn_global_load_lds(
      (const __attribute__((address_space(1))) void*)g,
      (__attribute__((address_space(3))) void*)l, 16, 0, 0);
}

// ---------------------------------------------------------------------------
// Kernel 1 (merged): blocks 0..63 pack W_enc -> bf16 MFMA B-fragment order;
// blocks 64..191 compute att2[b][a] = dec[b]@W_dec[:,a] + b_dec[a] + b_enc[a].
// Bpack layout: [ki=0..15][nf=0..31][lane=0..63][j=0..7]  (chunk ki contiguous)
//   lane l holds B[k][n], k = ki*32 + (l>>4)*8 + j, n = nf*16 + (l&15)
__global__ void k_prep(const float* __restrict__ W_enc,
                       unsigned short* __restrict__ Bpack,
                       const float* __restrict__ dec,
                       const float* __restrict__ Wdec,
                       const float* __restrict__ b_enc,
                       const float* __restrict__ b_dec,
                       float* __restrict__ att2) {
  int blk = blockIdx.x;
  int tid = threadIdx.x;  // 512
  if (blk < 64) {
    int t = blk * 512 + tid;  // 0..32767
    int lane = t & 63;
    int rest = t >> 6;        // rest = ki*32 + nf
    int nf = rest & 31;
    int ki = rest >> 5;
    int col = nf * 16 + (lane & 15);
    int kbase = ki * 32 + (lane >> 4) * 8;
    short8 v;
#pragma unroll
    for (int j = 0; j < 8; ++j)
      v[j] = (short)f2bf(W_enc[(kbase + j) * NA + col]);
    *reinterpret_cast<short8*>(Bpack + (long)t * 8) = v;
  } else {
    int b = blk - 64;
    int a = tid;
    float acc = b_enc[a] + b_dec[a];
    const float* drow = dec + b * ND;
#pragma unroll 4
    for (int d = 0; d < ND; ++d)
      acc += drow[d] * Wdec[d * NA + a];
    att2[b * NA + a] = acc;
  }
}

// ---------------------------------------------------------------------------
// Kernel 2: fused scores GEMM. 512 thr (8 waves), BM=64 rows.
// A in LDS in FRAGMENT order: offset = ((rt*16+ki)*64 + (lane^(ki&7)))*16
//   -> both staging writes and ds_read_b128 are (XOR-permuted) linear.
// B double-buffered 32KB chunks via global_load_lds (no VGPR cost).
// Wave w: all 64 rows x cols [w*64, w*64+64) -> acc[4][4] (AGPR).
// Epilogue: relu(acc+att2)*W_full reduced over cols -> att[m] (b_full dropped).
__global__ __launch_bounds__(512, 2) void k_scores(
    const float* __restrict__ enc, const unsigned short* __restrict__ Bpack,
    const float* __restrict__ att2, const float* __restrict__ wfull,
    float* __restrict__ att) {
  extern __shared__ char smem[];
  // 0..65536:        A fragments (64 KB)
  // 65536 + b*32768: B chunk double buffer (2 x 32 KB)
  // 131072: a2row (2KB) | 133120: wf (2KB) | 135168: red (2KB)
  float* a2row = (float*)(smem + 131072);
  float* wf    = (float*)(smem + 133120);
  float* red   = (float*)(smem + 135168);

  const int t = threadIdx.x;
  const int lane = t & 63;
  const int wave = t >> 6;
  const int blk = blockIdx.x;
  const long row0 = (long)blk * 64;
  const int b = blk >> 4;   // 1024 rows per batch

  // ---- prologue: kick off B chunk ki=0 into buf0 (async DMA) ----
#pragma unroll
  for (int r = 0; r < 4; ++r) {
    int nf = wave * 4 + r;
    async_cp16(Bpack + ((long)(0 * 32 + nf) * 64 + lane) * 8,
               smem + 65536 + nf * 1024 + lane * 16);
  }

  // ---- stage A: 64 rows x 512 k fp32 -> bf16 fragments ----
  {
    const int rsub = (wave & 3) * 2 + (lane >> 5);       // 0..7
    const int kchunk = (wave >> 2) * 32 + (lane & 31);   // 0..63
    const int ki = kchunk >> 2;
    const int lhi = kchunk & 3;
    const float* src0 = enc + row0 * NE;
#pragma unroll
    for (int i = 0; i < 8; ++i) {
      int row = i * 8 + rsub;
      const float4* p =
          reinterpret_cast<const float4*>(src0 + (long)row * NE + kchunk * 8);
      float4 x0 = p[0];
      float4 x1 = p[1];
      short8 o;
      o[0] = (short)f2bf(x0.x); o[1] = (short)f2bf(x0.y);
      o[2] = (short)f2bf(x0.z); o[3] = (short)f2bf(x0.w);
      o[4] = (short)f2bf(x1.x); o[5] = (short)f2bf(x1.y);
      o[6] = (short)f2bf(x1.z); o[7] = (short)f2bf(x1.w);
      int rt = row >> 4;
      int idx = (lhi * 16 + (row & 15)) ^ (ki & 7);
      *reinterpret_cast<short8*>(smem + ((rt * 16 + ki) * 64 + idx) * 16) = o;
    }
    if (t < 256) {
      a2row[t]       = att2[b * NA + t];
      a2row[t + 256] = att2[b * NA + t + 256];
    } else {
      int u = t - 256;
      wf[u]          = wfull[u];
      wf[u + 256]    = wfull[u + 256];
    }
  }
  __syncthreads();   // drains vmcnt(0): buf0 staged; A fragments visible

  f32x4 acc[4][4];
#pragma unroll
  for (int rt = 0; rt < 4; ++rt)
#pragma unroll
    for (int cf = 0; cf < 4; ++cf) acc[rt][cf] = (f32x4){0.f, 0.f, 0.f, 0.f};

#pragma unroll
  for (int ki = 0; ki < 16; ++ki) {
    const int curbuf = 65536 + (ki & 1) * 32768;
    const int nxtbuf = 65536 + ((ki + 1) & 1) * 32768;
    if (ki < 15) {  // issue next chunk's DMA first, let it fly under compute
#pragma unroll
      for (int r = 0; r < 4; ++r) {
        int nf = wave * 4 + r;
        async_cp16(Bpack + ((long)((ki + 1) * 32 + nf) * 64 + lane) * 8,
                   smem + nxtbuf + nf * 1024 + lane * 16);
      }
    }
    short8 av[4], bv[4];
#pragma unroll
    for (int cf = 0; cf < 4; ++cf)
      bv[cf] = *reinterpret_cast<const short8*>(
          smem + curbuf + (wave * 4 + cf) * 1024 + lane * 16);
#pragma unroll
    for (int rt = 0; rt < 4; ++rt)
      av[rt] = *reinterpret_cast<const short8*>(
          smem + ((rt * 16 + ki) * 64 + (lane ^ (ki & 7))) * 16);
#pragma unroll
    for (int rt = 0; rt < 4; ++rt)
#pragma unroll
      for (int cf = 0; cf < 4; ++cf)
        acc[rt][cf] = __builtin_amdgcn_mfma_f32_16x16x32_bf16(
            av[rt], bv[cf], acc[rt][cf], 0, 0, 0);
    __syncthreads();  // vmcnt(0)+lgkmcnt(0) drain: next buf ready, cur buf free
  }

  // Epilogue: relu + project + reduce over this wave's 64 cols.
  // C layout: row = rt*16 + (lane>>4)*4 + r, col = wave*64 + cf*16 + (lane&15).
  const int l15 = lane & 15;
  const int lq = lane >> 4;
  float partial[4][4];
#pragma unroll
  for (int rt = 0; rt < 4; ++rt)
#pragma unroll
    for (int r = 0; r < 4; ++r) partial[rt][r] = 0.f;

#pragma unroll
  for (int cf = 0; cf < 4; ++cf) {
    int col = wave * 64 + cf * 16 + l15;
    float a2 = a2row[col];
    float w = wf[col];
#pragma unroll
    for (int rt = 0; rt < 4; ++rt)
#pragma unroll
      for (int r = 0; r < 4; ++r) {
        float v = acc[rt][cf][r] + a2;
        partial[rt][r] += fmaxf(v, 0.f) * w;
      }
  }
#pragma unroll
  for (int rt = 0; rt < 4; ++rt)
#pragma unroll
    for (int r = 0; r < 4; ++r) {
      float p = partial[rt][r];
      p += __shfl_xor(p, 1);
      p += __shfl_xor(p, 2);
      p += __shfl_xor(p, 4);
      p += __shfl_xor(p, 8);
      partial[rt][r] = p;
    }
  if (l15 == 0) {
#pragma unroll
    for (int rt = 0; rt < 4; ++rt)
#pragma unroll
      for (int r = 0; r < 4; ++r)
        red[wave * 64 + rt * 16 + lq * 4 + r] = partial[rt][r];
  }
  __syncthreads();
  if (t < 64) {
    float s = 0.f;
#pragma unroll
    for (int w = 0; w < 8; ++w) s += red[w * 64 + t];
    att[row0 + t] = s;
  }
}

// ---------------------------------------------------------------------------
// Kernel 3: softmax over L=1024 per batch row. alpha written to d_out.
__global__ void k_softmax(const float* __restrict__ att,
                          float* __restrict__ alpha) {
  int b = blockIdx.x;
  int t = threadIdx.x;  // 256
  const float* row = att + b * NL;
  float v0 = row[t], v1 = row[t + 256], v2 = row[t + 512], v3 = row[t + 768];
  float m = fmaxf(fmaxf(v0, v1), fmaxf(v2, v3));
#pragma unroll
  for (int off = 1; off < 64; off <<= 1) m = fmaxf(m, __shfl_xor(m, off));
  __shared__ float rm[4];
  int lane = t & 63, w = t >> 6;
  if (lane == 0) rm[w] = m;
  __syncthreads();
  m = fmaxf(fmaxf(rm[0], rm[1]), fmaxf(rm[2], rm[3]));
  float e0 = expf(v0 - m), e1 = expf(v1 - m), e2 = expf(v2 - m), e3 = expf(v3 - m);
  float s = e0 + e1 + e2 + e3;
#pragma unroll
  for (int off = 1; off < 64; off <<= 1) s += __shfl_xor(s, off);
  __shared__ float rs[4];
  if (lane == 0) rs[w] = s;
  __syncthreads();
  s = rs[0] + rs[1] + rs[2] + rs[3];
  float inv = 1.f / s;
  float* arow = alpha + b * NL;
  arow[t] = e0 * inv;
  arow[t + 256] = e1 * inv;
  arow[t + 512] = e2 * inv;
  arow[t + 768] = e3 * inv;
}

// ---------------------------------------------------------------------------
// Kernel 4: partial weighted sum. Grid = 128 b * 16 l-chunks, 128 threads.
__global__ void k_wpart(const float* __restrict__ enc,
                        const float* __restrict__ alpha,
                        float* __restrict__ part) {
  int bid = blockIdx.x;          // 0..2047
  int b = bid >> 4, lc = bid & 15;
  int t = threadIdx.x;           // 0..127
  const float* base = enc + ((long)b * NL + lc * 64) * NE;
  const float* al = alpha + b * NL + lc * 64;
  float4 s = {0.f, 0.f, 0.f, 0.f};
#pragma unroll 4
  for (int l = 0; l < 64; ++l) {
    float a = al[l];
    const float4 x = *reinterpret_cast<const float4*>(base + (long)l * NE + t * 4);
    s.x += a * x.x;
    s.y += a * x.y;
    s.z += a * x.z;
    s.w += a * x.w;
  }
  *reinterpret_cast<float4*>(part + (long)bid * NE + t * 4) = s;
}

// ---------------------------------------------------------------------------
// Kernel 5: reduce 16 l-chunk partials -> weighted [B,E] into d_out.
__global__ void k_wreduce(const float* __restrict__ part,
                          float* __restrict__ outw) {
  int g = blockIdx.x * 256 + threadIdx.x;  // 0..65535
  int b = g >> 9, e = g & 511;
  float s = 0.f;
#pragma unroll
  for (int lc = 0; lc < 16; ++lc) s += part[(long)(b * 16 + lc) * NE + e];
  outw[g] = s;
}

// ---------------------------------------------------------------------------
extern "C" void kernel_launch(void* const* d_in, const int* in_sizes, int n_in,
                              void* d_out, int out_size, void* d_ws, size_t ws_size,
                              hipStream_t stream) {
  const float* enc    = (const float*)d_in[0];  // [B,L,E]
  const float* dec    = (const float*)d_in[1];  // [B,D]
  const float* W_enc  = (const float*)d_in[2];  // [E,A]
  const float* b_enc  = (const float*)d_in[3];  // [A]
  const float* W_dec  = (const float*)d_in[4];  // [D,A]
  const float* b_dec  = (const float*)d_in[5];  // [A]
  const float* W_full = (const float*)d_in[6];  // [A]
  // d_in[7] = b_full: cancels in softmax, unused.

  float* out = (float*)d_out;
  float* weighted = out;                 // [B,E] = 65536
  float* alpha = out + NB * NE;          // [B,L] = 131072

  char* ws = (char*)d_ws;
  float* att2          = (float*)ws;                                   // 256 KB
  unsigned short* Bpk  = (unsigned short*)(ws + (256 << 10));          // 512 KB
  float* att           = (float*)(ws + (768 << 10));                   // 512 KB
  float* part          = (float*)(ws + (1280 << 10));                  // 4 MB

  hipLaunchKernelGGL(k_prep, dim3(192), dim3(512), 0, stream,
                     W_enc, Bpk, dec, W_dec, b_enc, b_dec, att2);
  hipLaunchKernelGGL(k_scores, dim3((NB * NL) / 64), dim3(512), 137216, stream,
                     enc, Bpk, att2, W_full, att);
  hipLaunchKernelGGL(k_softmax, dim3(NB), dim3(256), 0, stream, att, alpha);
  hipLaunchKernelGGL(k_wpart, dim3(NB * 16), dim3(128), 0, stream, enc, alpha, part);
  hipLaunchKernelGGL(k_wreduce, dim3(NB * NE / 256), dim3(256), 0, stream, part, weighted);
}

// Round 5
// 216.212 us; speedup vs baseline: 1.1443x; 1.1443x over previous
//
#include <hip/hip_runtime.h>

// Problem constants
#define NB 128
#define NL 1024
#define NE 512
#define NA 512
#define ND 512

typedef __attribute__((ext_vector_type(8))) short short8;
typedef __attribute__((ext_vector_type(4))) float f32x4;

static __device__ __forceinline__ unsigned short f2bf(float f) {
  unsigned int u = __float_as_uint(f);
  u += 0x7FFF + ((u >> 16) & 1);   // round-to-nearest-even
  return (unsigned short)(u >> 16);
}

// async global->LDS, 16B per lane (wave-uniform LDS base + lane*16)
static __device__ __forceinline__ void async_cp16(const void* g, void* l) {
  __builtin_amdgcn_global_load_lds(
      (const __attribute__((address_space(1))) void*)g,
      (__attribute__((address_space(3))) void*)l, 16, 0, 0);
}

// ---------------------------------------------------------------------------
// Kernel 1 (merged): blocks 0..63 pack W_enc -> bf16 MFMA B-fragment order;
// blocks 64..191 compute att2[b][a] = dec[b]@W_dec[:,a] + b_dec[a] + b_enc[a].
// Bpack layout: [ki=0..15][nf=0..31][lane=0..63][j=0..7]  (chunk ki contiguous)
//   lane l holds B[k][n], k = ki*32 + (l>>4)*8 + j, n = nf*16 + (l&15)
__global__ void k_prep(const float* __restrict__ W_enc,
                       unsigned short* __restrict__ Bpack,
                       const float* __restrict__ dec,
                       const float* __restrict__ Wdec,
                       const float* __restrict__ b_enc,
                       const float* __restrict__ b_dec,
                       float* __restrict__ att2) {
  int blk = blockIdx.x;
  int tid = threadIdx.x;  // 512
  if (blk < 64) {
    int t = blk * 512 + tid;  // 0..32767
    int lane = t & 63;
    int rest = t >> 6;        // rest = ki*32 + nf
    int nf = rest & 31;
    int ki = rest >> 5;
    int col = nf * 16 + (lane & 15);
    int kbase = ki * 32 + (lane >> 4) * 8;
    short8 v;
#pragma unroll
    for (int j = 0; j < 8; ++j)
      v[j] = (short)f2bf(W_enc[(kbase + j) * NA + col]);
    *reinterpret_cast<short8*>(Bpack + (long)t * 8) = v;
  } else {
    int b = blk - 64;
    int a = tid;
    float acc = b_enc[a] + b_dec[a];
    const float* drow = dec + b * ND;
#pragma unroll 4
    for (int d = 0; d < ND; ++d)
      acc += drow[d] * Wdec[d * NA + a];
    att2[b * NA + a] = acc;
  }
}

// ---------------------------------------------------------------------------
// Kernel 2: fused scores GEMM. 512 thr (8 waves), BM=64 rows.
// A in LDS in fragment order (frag (rt,ki) = 1KB at (rt*16+ki)*1024, lane*16)
//   -> staging writes AND frag reads are perfectly linear (0 bank conflicts).
// B: wave-PRIVATE depth-3 LDS ring fed by global_load_lds; each wave issues
// and consumes only its own 4 fragments per ki -> per-wave counted vmcnt,
// NO barriers in the K-loop (T3/T4: never drain vmcnt to 0).
// Epilogue: relu(acc+att2)*W_full reduced over cols -> att[m] (b_full dropped).
__global__ __launch_bounds__(512, 2) void k_scores(
    const float* __restrict__ enc, const unsigned short* __restrict__ Bpack,
    const float* __restrict__ att2g, const float* __restrict__ wfull,
    float* __restrict__ att) {
  extern __shared__ char smem[];
  // 0..65536:  A fragments (64 KB)
  // 65536 + slot*32768 + wave*4096 + cf*1024: B ring (3 x 32 KB)
  const int t = threadIdx.x;
  const int lane = t & 63;
  const int wave = t >> 6;
  const int l15 = lane & 15;
  const int lq = lane >> 4;
  const int blk = blockIdx.x;
  const long row0 = (long)blk * 64;
  const int b = blk >> 4;   // 1024 rows per batch

#define B_ISSUE(KI2, SLOT)                                                    \
  {                                                                           \
    const unsigned short* bsrc =                                              \
        Bpack + (((long)(KI2)*32 + wave * 4) * 64 + lane) * 8;                \
    char* bdst = smem + 65536 + (SLOT)*32768 + wave * 4096 + lane * 16;       \
    async_cp16(bsrc, bdst);                                                   \
    async_cp16(bsrc + 512, bdst + 1024);                                      \
    async_cp16(bsrc + 1024, bdst + 2048);                                     \
    async_cp16(bsrc + 1536, bdst + 3072);                                     \
  }

  // ---- prologue: chunk 0 DMA in flight during A staging ----
  B_ISSUE(0, 0);

  // ---- stage A: wave w, iter it handles fragment fr = it*8+w.
  // Lane reads enc[row][k0..k0+8) (wave = one full 2KB row, coalesced),
  // writes the 1KB fragment linearly at lane*16 (conflict-free).
  {
    float4 f[16];
#pragma unroll
    for (int it = 0; it < 8; ++it) {
      int fr = it * 8 + wave;
      int row = (fr >> 4) * 16 + l15;
      int k0 = (fr & 15) * 32 + lq * 8;
      const float4* p =
          reinterpret_cast<const float4*>(enc + (row0 + row) * NE + k0);
      f[it * 2] = p[0];
      f[it * 2 + 1] = p[1];
    }
#pragma unroll
    for (int it = 0; it < 8; ++it) {
      int fr = it * 8 + wave;
      float4 x0 = f[it * 2], x1 = f[it * 2 + 1];
      short8 o;
      o[0] = (short)f2bf(x0.x); o[1] = (short)f2bf(x0.y);
      o[2] = (short)f2bf(x0.z); o[3] = (short)f2bf(x0.w);
      o[4] = (short)f2bf(x1.x); o[5] = (short)f2bf(x1.y);
      o[6] = (short)f2bf(x1.z); o[7] = (short)f2bf(x1.w);
      *reinterpret_cast<short8*>(smem + fr * 1024 + lane * 16) = o;
    }
  }
  __syncthreads();   // drains vmcnt(0): chunk0 in LDS; A fragments visible

  B_ISSUE(1, 1);     // chunk 1 in flight

  f32x4 acc[4][4];
#pragma unroll
  for (int rt = 0; rt < 4; ++rt)
#pragma unroll
    for (int cf = 0; cf < 4; ++cf) acc[rt][cf] = (f32x4){0.f, 0.f, 0.f, 0.f};

#define K_STEP(KI, VMSTR)                                                     \
  {                                                                           \
    if ((KI) + 2 < 16) B_ISSUE((KI) + 2, ((KI) + 2) % 3);                     \
    asm volatile("s_waitcnt vmcnt(" VMSTR ")" ::: "memory");                  \
    const char* bbase =                                                       \
        smem + 65536 + ((KI) % 3) * 32768 + wave * 4096 + lane * 16;          \
    short8 bv0 = *reinterpret_cast<const short8*>(bbase);                     \
    short8 bv1 = *reinterpret_cast<const short8*>(bbase + 1024);              \
    short8 bv2 = *reinterpret_cast<const short8*>(bbase + 2048);              \
    short8 bv3 = *reinterpret_cast<const short8*>(bbase + 3072);              \
    const char* abase = smem + (KI)*1024 + lane * 16;                         \
    short8 av0 = *reinterpret_cast<const short8*>(abase);                     \
    short8 av1 = *reinterpret_cast<const short8*>(abase + 16384);             \
    short8 av2 = *reinterpret_cast<const short8*>(abase + 32768);             \
    short8 av3 = *reinterpret_cast<const short8*>(abase + 49152);             \
    acc[0][0] = __builtin_amdgcn_mfma_f32_16x16x32_bf16(av0, bv0, acc[0][0], 0, 0, 0); \
    acc[0][1] = __builtin_amdgcn_mfma_f32_16x16x32_bf16(av0, bv1, acc[0][1], 0, 0, 0); \
    acc[0][2] = __builtin_amdgcn_mfma_f32_16x16x32_bf16(av0, bv2, acc[0][2], 0, 0, 0); \
    acc[0][3] = __builtin_amdgcn_mfma_f32_16x16x32_bf16(av0, bv3, acc[0][3], 0, 0, 0); \
    acc[1][0] = __builtin_amdgcn_mfma_f32_16x16x32_bf16(av1, bv0, acc[1][0], 0, 0, 0); \
    acc[1][1] = __builtin_amdgcn_mfma_f32_16x16x32_bf16(av1, bv1, acc[1][1], 0, 0, 0); \
    acc[1][2] = __builtin_amdgcn_mfma_f32_16x16x32_bf16(av1, bv2, acc[1][2], 0, 0, 0); \
    acc[1][3] = __builtin_amdgcn_mfma_f32_16x16x32_bf16(av1, bv3, acc[1][3], 0, 0, 0); \
    acc[2][0] = __builtin_amdgcn_mfma_f32_16x16x32_bf16(av2, bv0, acc[2][0], 0, 0, 0); \
    acc[2][1] = __builtin_amdgcn_mfma_f32_16x16x32_bf16(av2, bv1, acc[2][1], 0, 0, 0); \
    acc[2][2] = __builtin_amdgcn_mfma_f32_16x16x32_bf16(av2, bv2, acc[2][2], 0, 0, 0); \
    acc[2][3] = __builtin_amdgcn_mfma_f32_16x16x32_bf16(av2, bv3, acc[2][3], 0, 0, 0); \
    acc[3][0] = __builtin_amdgcn_mfma_f32_16x16x32_bf16(av3, bv0, acc[3][0], 0, 0, 0); \
    acc[3][1] = __builtin_amdgcn_mfma_f32_16x16x32_bf16(av3, bv1, acc[3][1], 0, 0, 0); \
    acc[3][2] = __builtin_amdgcn_mfma_f32_16x16x32_bf16(av3, bv2, acc[3][2], 0, 0, 0); \
    acc[3][3] = __builtin_amdgcn_mfma_f32_16x16x32_bf16(av3, bv3, acc[3][3], 0, 0, 0); \
  }

  // Steady state: 2 chunks (8 loads) in flight -> wait vmcnt(8).
  K_STEP(0, "8")  K_STEP(1, "8")  K_STEP(2, "8")  K_STEP(3, "8")
  K_STEP(4, "8")  K_STEP(5, "8")  K_STEP(6, "8")  K_STEP(7, "8")
  K_STEP(8, "8")  K_STEP(9, "8")  K_STEP(10, "8") K_STEP(11, "8")
  K_STEP(12, "8") K_STEP(13, "8") K_STEP(14, "4") K_STEP(15, "0")

  // Epilogue: relu + project + reduce over this wave's 64 cols.
  // C layout: row = rt*16 + lq*4 + r, col = wave*64 + cf*16 + l15.
  float partial[4][4];
#pragma unroll
  for (int rt = 0; rt < 4; ++rt)
#pragma unroll
    for (int r = 0; r < 4; ++r) partial[rt][r] = 0.f;

#pragma unroll
  for (int cf = 0; cf < 4; ++cf) {
    int col = wave * 64 + cf * 16 + l15;
    float a2 = att2g[b * NA + col];
    float w = wfull[col];
#pragma unroll
    for (int rt = 0; rt < 4; ++rt)
#pragma unroll
      for (int r = 0; r < 4; ++r) {
        float v = acc[rt][cf][r] + a2;
        partial[rt][r] += fmaxf(v, 0.f) * w;
      }
  }
#pragma unroll
  for (int rt = 0; rt < 4; ++rt)
#pragma unroll
    for (int r = 0; r < 4; ++r) {
      float p = partial[rt][r];
      p += __shfl_xor(p, 1);
      p += __shfl_xor(p, 2);
      p += __shfl_xor(p, 4);
      p += __shfl_xor(p, 8);
      partial[rt][r] = p;
    }

  __syncthreads();   // all waves done with ring slot 0 before reuse as red
  float* red = (float*)(smem + 65536);   // 8 waves x 64 rows
  if (l15 == 0) {
#pragma unroll
    for (int rt = 0; rt < 4; ++rt)
#pragma unroll
      for (int r = 0; r < 4; ++r)
        red[wave * 64 + rt * 16 + lq * 4 + r] = partial[rt][r];
  }
  __syncthreads();
  if (t < 64) {
    float s = 0.f;
#pragma unroll
    for (int w = 0; w < 8; ++w) s += red[w * 64 + t];
    att[row0 + t] = s;
  }
#undef K_STEP
#undef B_ISSUE
}

// ---------------------------------------------------------------------------
// Kernel 3: softmax over L=1024 per batch row. alpha written to d_out.
__global__ void k_softmax(const float* __restrict__ att,
                          float* __restrict__ alpha) {
  int b = blockIdx.x;
  int t = threadIdx.x;  // 256
  const float* row = att + b * NL;
  float v0 = row[t], v1 = row[t + 256], v2 = row[t + 512], v3 = row[t + 768];
  float m = fmaxf(fmaxf(v0, v1), fmaxf(v2, v3));
#pragma unroll
  for (int off = 1; off < 64; off <<= 1) m = fmaxf(m, __shfl_xor(m, off));
  __shared__ float rm[4];
  int lane = t & 63, w = t >> 6;
  if (lane == 0) rm[w] = m;
  __syncthreads();
  m = fmaxf(fmaxf(rm[0], rm[1]), fmaxf(rm[2], rm[3]));
  float e0 = expf(v0 - m), e1 = expf(v1 - m), e2 = expf(v2 - m), e3 = expf(v3 - m);
  float s = e0 + e1 + e2 + e3;
#pragma unroll
  for (int off = 1; off < 64; off <<= 1) s += __shfl_xor(s, off);
  __shared__ float rs[4];
  if (lane == 0) rs[w] = s;
  __syncthreads();
  s = rs[0] + rs[1] + rs[2] + rs[3];
  float inv = 1.f / s;
  float* arow = alpha + b * NL;
  arow[t] = e0 * inv;
  arow[t + 256] = e1 * inv;
  arow[t + 512] = e2 * inv;
  arow[t + 768] = e3 * inv;
}

// ---------------------------------------------------------------------------
// Kernel 4: partial weighted sum. Grid = 128 b * 16 l-chunks, 128 threads.
__global__ void k_wpart(const float* __restrict__ enc,
                        const float* __restrict__ alpha,
                        float* __restrict__ part) {
  int bid = blockIdx.x;          // 0..2047
  int b = bid >> 4, lc = bid & 15;
  int t = threadIdx.x;           // 0..127
  const float* base = enc + ((long)b * NL + lc * 64) * NE;
  const float* al = alpha + b * NL + lc * 64;
  float4 s = {0.f, 0.f, 0.f, 0.f};
#pragma unroll 4
  for (int l = 0; l < 64; ++l) {
    float a = al[l];
    const float4 x = *reinterpret_cast<const float4*>(base + (long)l * NE + t * 4);
    s.x += a * x.x;
    s.y += a * x.y;
    s.z += a * x.z;
    s.w += a * x.w;
  }
  *reinterpret_cast<float4*>(part + (long)bid * NE + t * 4) = s;
}

// ---------------------------------------------------------------------------
// Kernel 5: reduce 16 l-chunk partials -> weighted [B,E] into d_out.
__global__ void k_wreduce(const float* __restrict__ part,
                          float* __restrict__ outw) {
  int g = blockIdx.x * 256 + threadIdx.x;  // 0..65535
  int b = g >> 9, e = g & 511;
  float s = 0.f;
#pragma unroll
  for (int lc = 0; lc < 16; ++lc) s += part[(long)(b * 16 + lc) * NE + e];
  outw[g] = s;
}

// ---------------------------------------------------------------------------
extern "C" void kernel_launch(void* const* d_in, const int* in_sizes, int n_in,
                              void* d_out, int out_size, void* d_ws, size_t ws_size,
                              hipStream_t stream) {
  const float* enc    = (const float*)d_in[0];  // [B,L,E]
  const float* dec    = (const float*)d_in[1];  // [B,D]
  const float* W_enc  = (const float*)d_in[2];  // [E,A]
  const float* b_enc  = (const float*)d_in[3];  // [A]
  const float* W_dec  = (const float*)d_in[4];  // [D,A]
  const float* b_dec  = (const float*)d_in[5];  // [A]
  const float* W_full = (const float*)d_in[6];  // [A]
  // d_in[7] = b_full: cancels in softmax, unused.

  float* out = (float*)d_out;
  float* weighted = out;                 // [B,E] = 65536
  float* alpha = out + NB * NE;          // [B,L] = 131072

  char* ws = (char*)d_ws;
  float* att2          = (float*)ws;                                   // 256 KB
  unsigned short* Bpk  = (unsigned short*)(ws + (256 << 10));          // 512 KB
  float* att           = (float*)(ws + (768 << 10));                   // 512 KB
  float* part          = (float*)(ws + (1280 << 10));                  // 4 MB

  hipLaunchKernelGGL(k_prep, dim3(192), dim3(512), 0, stream,
                     W_enc, Bpk, dec, W_dec, b_enc, b_dec, att2);
  hipLaunchKernelGGL(k_scores, dim3((NB * NL) / 64), dim3(512), 163840, stream,
                     enc, Bpk, att2, W_full, att);
  hipLaunchKernelGGL(k_softmax, dim3(NB), dim3(256), 0, stream, att, alpha);
  hipLaunchKernelGGL(k_wpart, dim3(NB * 16), dim3(128), 0, stream, enc, alpha, part);
  hipLaunchKernelGGL(k_wreduce, dim3(NB * NE / 256), dim3(256), 0, stream, part, weighted);
}